// Round 5
// baseline (250.162 us; speedup 1.0000x reference)
//
#include <hip/hip_runtime.h>

// positions [N,3] f32, node_feat [N,1] f32, w0 [1] f32, w1 [3] f32,
// edge_src [E] i32, edge_dst [E] i32  ->  out [N,4] f32
//
// Strategy (R5): eliminate global atomics entirely (measured hard cap
// ~22 G ops/s = one 32 B EA transaction per op, scope-insensitive).
// Node space is split into NCHUNK chunks of CHUNK=8064 nodes; each
// workgroup = (chunk c, edge-slice s). It streams slice s's dst[] once,
// and for edges with dst in chunk c accumulates a packed u64 into an LDS
// table (64 KB, u64 atomics in LDS are banked/cheap). Flush = plain
// coalesced stores into per-slice replica accR[s][node]; finalize sums
// the S replicas. Zero global atomics, no workspace memset needed.
//
// Packed fixed-point per edge (same as R3, verified absmax 7.8e-3):
//   bits 48..63 : 128 + round(sh.x*128)  in [0,256]
//   bits 32..47 : 128 + round(sh.y*128)
//   bits 16..31 : 128 + round(sh.z*128)
//   bits  0..15 : 1 (count)
// Per-(node,slice) field sums <= 256*deg_max(~60) << 65536 -> no carry.
// Decode: sum_sh = F/128 - count.

#define EPS 1e-12f
#define FSCALE 128.0f
#define FBIAS 128
#define CHUNK 8064
#define BLOCK 512

__device__ __forceinline__ unsigned long long pack_edge(const float* __restrict__ pos,
                                                        int s, int d) {
    float rx = pos[3 * d + 0] - pos[3 * s + 0];
    float ry = pos[3 * d + 1] - pos[3 * s + 1];
    float rz = pos[3 * d + 2] - pos[3 * s + 2];
    float nrm = sqrtf(rx * rx + ry * ry + rz * rz);
    float inv = 1.0f / fmaxf(nrm, EPS);
    unsigned fx = (unsigned)(FBIAS + (int)rintf(rx * inv * FSCALE));
    unsigned fy = (unsigned)(FBIAS + (int)rintf(ry * inv * FSCALE));
    unsigned fz = (unsigned)(FBIAS + (int)rintf(rz * inv * FSCALE));
    return ((unsigned long long)fx << 48) | ((unsigned long long)fy << 32)
         | ((unsigned long long)fz << 16) | 1ull;
}

__global__ __launch_bounds__(BLOCK) void edge_binned(
        const float* __restrict__ pos,
        const int* __restrict__ dst,
        const int* __restrict__ src,
        unsigned long long* __restrict__ accR,   // [S][padded]
        int n_edges, int n_chunk, int S, int padded) {
    __shared__ unsigned long long lds[CHUNK];
    int c = (int)blockIdx.x % n_chunk;   // consecutive blocks share an edge
    int s = (int)blockIdx.x / n_chunk;   // slice -> dst stream stays hot in L2/L3
    int lo = c * CHUNK;

    for (int i = threadIdx.x; i < CHUNK; i += BLOCK) lds[i] = 0ull;
    __syncthreads();

    long e0 = (long)n_edges * s / S;
    long e1 = (long)n_edges * (s + 1) / S;
    for (long j = e0 + threadIdx.x; j < e1; j += BLOCK) {
        int d = dst[j];
        unsigned local = (unsigned)(d - lo);
        if (local < (unsigned)CHUNK) {
            int sv = src[j];
            unsigned long long p = pack_edge(pos, sv, d);
            atomicAdd(&lds[local], p);
        }
    }
    __syncthreads();

    unsigned long long* row = accR + (size_t)s * (unsigned)padded + (unsigned)lo;
    for (int i = threadIdx.x; i < CHUNK; i += BLOCK) row[i] = lds[i];
}

__global__ void finalize_binned(const unsigned long long* __restrict__ accR,
                                const float* __restrict__ feat,
                                const float* __restrict__ w0,
                                const float* __restrict__ w1,
                                float* __restrict__ out,
                                int n_nodes, int S, int padded) {
    int n = blockIdx.x * blockDim.x + threadIdx.x;
    if (n >= n_nodes) return;
    int Fx = 0, Fy = 0, Fz = 0, C = 0;
    for (int s = 0; s < S; ++s) {
        unsigned long long v = accR[(size_t)s * (unsigned)padded + (unsigned)n];
        Fx += (int)(v >> 48);
        Fy += (int)((v >> 32) & 0xffffull);
        Fz += (int)((v >> 16) & 0xffffull);
        C  += (int)(v & 0xffffull);
    }
    float c = (float)C;
    float rd = 1.0f / fmaxf(c, 1.0f);
    float sx = (float)Fx * (1.0f / FSCALE) - c;
    float sy = (float)Fy * (1.0f / FSCALE) - c;
    float sz = (float)Fz * (1.0f / FSCALE) - c;
    float f = feat[n];
    float4 o;
    o.x = w0[0] * f * c * rd;
    o.y = w1[0] * f * sx * rd;
    o.z = w1[1] * f * sy * rd;
    o.w = w1[2] * f * sz * rd;
    ((float4*)out)[n] = o;
}

// ---- fallback (R3 structure): agent-scope packed atomics, known-good ----
__global__ void edge_kernel_agent(const float* __restrict__ pos,
                                  const int* __restrict__ dst,
                                  const int* __restrict__ src,
                                  unsigned long long* __restrict__ acc,
                                  int n_edges, int n_nodes, int rmask) {
    int i = blockIdx.x * blockDim.x + threadIdx.x;
    if (i >= n_edges) return;
    int s = src[i];
    int d = dst[i];
    unsigned long long p = pack_edge(pos, s, d);
    unsigned r = (unsigned)blockIdx.x & (unsigned)rmask;
    atomicAdd(acc + (size_t)r * (unsigned)n_nodes + (unsigned)d, p);
}

__global__ void finalize_flat(const unsigned long long* __restrict__ acc,
                              const float* __restrict__ feat,
                              const float* __restrict__ w0,
                              const float* __restrict__ w1,
                              float* __restrict__ out,
                              int n_nodes, int R) {
    int n = blockIdx.x * blockDim.x + threadIdx.x;
    if (n >= n_nodes) return;
    int Fx = 0, Fy = 0, Fz = 0, C = 0;
    for (int r = 0; r < R; ++r) {
        unsigned long long v = acc[(size_t)r * n_nodes + n];
        Fx += (int)(v >> 48);
        Fy += (int)((v >> 32) & 0xffffull);
        Fz += (int)((v >> 16) & 0xffffull);
        C  += (int)(v & 0xffffull);
    }
    float c = (float)C;
    float rd = 1.0f / fmaxf(c, 1.0f);
    float sx = (float)Fx * (1.0f / FSCALE) - c;
    float sy = (float)Fy * (1.0f / FSCALE) - c;
    float sz = (float)Fz * (1.0f / FSCALE) - c;
    float f = feat[n];
    float4 o;
    o.x = w0[0] * f * c * rd;
    o.y = w1[0] * f * sx * rd;
    o.z = w1[1] * f * sy * rd;
    o.w = w1[2] * f * sz * rd;
    ((float4*)out)[n] = o;
}

extern "C" void kernel_launch(void* const* d_in, const int* in_sizes, int n_in,
                              void* d_out, int out_size, void* d_ws, size_t ws_size,
                              hipStream_t stream) {
    const float* pos  = (const float*)d_in[0];
    const float* feat = (const float*)d_in[1];
    const float* w0   = (const float*)d_in[2];
    const float* w1   = (const float*)d_in[3];
    const int* esrc   = (const int*)d_in[4];
    const int* edst   = (const int*)d_in[5];
    int n_nodes = in_sizes[0] / 3;
    int n_edges = in_sizes[4];

    int n_chunk = (n_nodes + CHUNK - 1) / CHUNK;            // 13 for 100k
    int padded  = n_chunk * CHUNK;
    size_t row_bytes = (size_t)padded * sizeof(unsigned long long);

    int S = 512 / n_chunk;                                   // 2 wg/CU slots
    if (S < 1) S = 1;
    while (S > 1 && (size_t)S * row_bytes > ws_size) --S;

    int nb = 256;
    int ng = (n_nodes + nb - 1) / nb;

    if (S >= 8) {
        // binned path: zero global atomics, no memset needed
        unsigned long long* accR = (unsigned long long*)d_ws;
        dim3 grid(n_chunk * S);
        edge_binned<<<grid, BLOCK, 0, stream>>>(pos, edst, esrc, accR,
                                                n_edges, n_chunk, S, padded);
        finalize_binned<<<ng, nb, 0, stream>>>(accR, feat, w0, w1,
                                               (float*)d_out, n_nodes, S, padded);
    } else {
        // fallback: R3 known-good agent-atomic path
        int R = 4;
        while (R > 1 && (size_t)R * n_nodes * sizeof(unsigned long long) > ws_size) R >>= 1;
        unsigned long long* acc = (unsigned long long*)d_ws;
        hipMemsetAsync(acc, 0, (size_t)R * n_nodes * sizeof(unsigned long long), stream);
        int eb = 256;
        int eg = (n_edges + eb - 1) / eb;
        edge_kernel_agent<<<eg, eb, 0, stream>>>(pos, edst, esrc, acc,
                                                 n_edges, n_nodes, R - 1);
        finalize_flat<<<ng, nb, 0, stream>>>(acc, feat, w0, w1,
                                             (float*)d_out, n_nodes, R);
    }
}

// Round 6
// 136.533 us; speedup vs baseline: 1.8322x; 1.8322x over previous
//
#include <hip/hip_runtime.h>

// positions [N,3] f32, node_feat [N,1] f32, w0 [1] f32, w1 [3] f32,
// edge_src [E] i32, edge_dst [E] i32  ->  out [N,4] f32
//
// R6: two-phase counting-sort by dst-chunk. Measured facts driving this:
//  - global atomics: hard cap ~22 G ops/s, 32 B EA transaction each,
//    scope/payload-insensitive (R1-R4). 3.2M ops -> 145 us floor. Avoid.
//  - brute filter (R5): 13x redundant dst streaming + wave divergence
//    (P(any lane hits) ~ 1) -> body executes every iter at 8% lane eff.
// Phase A touches each edge once (full lane efficiency), bins a packed
// record into per-chunk buckets (LDS histogram -> 13 returning global
// atomics PER BLOCK, ~20k total). Phase B accumulates each bucket into a
// 64 KB LDS table with cheap LDS atomics, flushes with plain stores.
//
// Record (u64):  local(13b) << 27 | fx(9b) << 18 | fy(9b) << 9 | fz(9b)
//   where f? = 128 + round(sh_? * 128) in [0,256].
// Accum cell (u64): fx<<48 | fy<<32 | fz<<16 | count  (16-bit fields;
//   per-(node,sub) count <= deg_max ~70 -> field sums < 18k << 65536).
// Decode: sum_sh = F/128 - count.   (absmax 7.8e-3, verified R3-R5)

#define EPS 1e-12f
#define FSCALE 128.0f
#define FBIAS 128
#define CHUNK_SHIFT 13
#define CHUNK 8192
#define NCHUNK_MAX 16
#define BLKA 512
#define TPA 4
#define BLKB 512
#define SUBS 39

__device__ __forceinline__ void sh_fields(const float* __restrict__ pos,
                                          int s, int d,
                                          unsigned& fx, unsigned& fy, unsigned& fz) {
    float rx = pos[3 * d + 0] - pos[3 * s + 0];
    float ry = pos[3 * d + 1] - pos[3 * s + 1];
    float rz = pos[3 * d + 2] - pos[3 * s + 2];
    float nrm = sqrtf(rx * rx + ry * ry + rz * rz);
    float inv = 1.0f / fmaxf(nrm, EPS);
    fx = (unsigned)(FBIAS + (int)rintf(rx * inv * FSCALE));
    fy = (unsigned)(FBIAS + (int)rintf(ry * inv * FSCALE));
    fz = (unsigned)(FBIAS + (int)rintf(rz * inv * FSCALE));
}

// ---------------- Phase A: bin edges into per-chunk record buckets --------
__global__ __launch_bounds__(BLKA) void phaseA(
        const float* __restrict__ pos,
        const int* __restrict__ dst,
        const int* __restrict__ src,
        unsigned* __restrict__ gcnt,                 // [n_chunk]
        unsigned long long* __restrict__ recs,       // [n_chunk][cap]
        int n_edges, int cap, int n_chunk) {
    __shared__ unsigned h[NCHUNK_MAX];
    __shared__ unsigned base[NCHUNK_MAX];
    int tid = threadIdx.x;
    if (tid < n_chunk) h[tid] = 0;
    __syncthreads();

    long e0 = (long)blockIdx.x * (BLKA * TPA);
    unsigned long long rec[TPA];
    int ch[TPA];
    unsigned rank[TPA];
    bool val[TPA];
#pragma unroll
    for (int t = 0; t < TPA; ++t) {
        long j = e0 + (long)t * BLKA + tid;
        val[t] = (j < n_edges);
        if (val[t]) {
            int d = dst[j];
            int s = src[j];
            unsigned fx, fy, fz;
            sh_fields(pos, s, d, fx, fy, fz);
            ch[t] = d >> CHUNK_SHIFT;
            unsigned local = (unsigned)d & (CHUNK - 1);
            rec[t] = ((unsigned long long)local << 27)
                   | ((unsigned long long)fx << 18)
                   | ((unsigned long long)fy << 9)
                   | (unsigned long long)fz;
            rank[t] = atomicAdd(&h[ch[t]], 1u);
        }
    }
    __syncthreads();
    if (tid < n_chunk) base[tid] = h[tid] ? atomicAdd(&gcnt[tid], h[tid]) : 0u;
    __syncthreads();
#pragma unroll
    for (int t = 0; t < TPA; ++t) {
        if (val[t]) {
            unsigned idx = base[ch[t]] + rank[t];
            if (idx < (unsigned)cap)
                recs[(size_t)ch[t] * (unsigned)cap + idx] = rec[t];
        }
    }
}

// ---------------- Phase B: accumulate one bucket slice into LDS ----------
__global__ __launch_bounds__(BLKB) void phaseB(
        const unsigned* __restrict__ gcnt,
        const unsigned long long* __restrict__ recs,
        unsigned long long* __restrict__ accR,       // [SUBS][n_chunk*CHUNK]
        int cap, int n_chunk, int padded) {
    __shared__ unsigned long long lds[CHUNK];
    int c   = (int)blockIdx.x % n_chunk;
    int sub = (int)blockIdx.x / n_chunk;
    unsigned cnt = gcnt[c];
    if (cnt > (unsigned)cap) cnt = (unsigned)cap;

    for (int i = threadIdx.x; i < CHUNK; i += BLKB) lds[i] = 0ull;
    __syncthreads();

    const unsigned long long* bucket = recs + (size_t)c * (unsigned)cap;
    for (unsigned j = sub * BLKB + threadIdx.x; j < cnt; j += SUBS * BLKB) {
        unsigned long long r = bucket[j];
        unsigned local = (unsigned)(r >> 27);
        unsigned long long p = (((r >> 18) & 511ull) << 48)
                             | (((r >>  9) & 511ull) << 32)
                             | (((r      ) & 511ull) << 16)
                             | 1ull;
        atomicAdd(&lds[local], p);
    }
    __syncthreads();

    unsigned long long* row = accR + (size_t)sub * (unsigned)padded
                                   + (size_t)c * CHUNK;
    for (int i = threadIdx.x; i < CHUNK; i += BLKB) row[i] = lds[i];
}

// ---------------- Finalize: merge replicas, decode, weight ---------------
__global__ void finalize_binned(const unsigned long long* __restrict__ accR,
                                const float* __restrict__ feat,
                                const float* __restrict__ w0,
                                const float* __restrict__ w1,
                                float* __restrict__ out,
                                int n_nodes, int padded) {
    int n = blockIdx.x * blockDim.x + threadIdx.x;
    if (n >= n_nodes) return;
    int Fx = 0, Fy = 0, Fz = 0, C = 0;
    for (int s = 0; s < SUBS; ++s) {
        unsigned long long v = accR[(size_t)s * (unsigned)padded + (unsigned)n];
        Fx += (int)(v >> 48);
        Fy += (int)((v >> 32) & 0xffffull);
        Fz += (int)((v >> 16) & 0xffffull);
        C  += (int)(v & 0xffffull);
    }
    float c = (float)C;
    float rd = 1.0f / fmaxf(c, 1.0f);
    float sx = (float)Fx * (1.0f / FSCALE) - c;
    float sy = (float)Fy * (1.0f / FSCALE) - c;
    float sz = (float)Fz * (1.0f / FSCALE) - c;
    float f = feat[n];
    float4 o;
    o.x = w0[0] * f * c * rd;
    o.y = w1[0] * f * sx * rd;
    o.z = w1[1] * f * sy * rd;
    o.w = w1[2] * f * sz * rd;
    ((float4*)out)[n] = o;
}

// ---------------- Fallback (R3, known-good 224 us) -----------------------
__global__ void edge_kernel_agent(const float* __restrict__ pos,
                                  const int* __restrict__ dst,
                                  const int* __restrict__ src,
                                  unsigned long long* __restrict__ acc,
                                  int n_edges, int n_nodes, int rmask) {
    int i = blockIdx.x * blockDim.x + threadIdx.x;
    if (i >= n_edges) return;
    int s = src[i];
    int d = dst[i];
    unsigned fx, fy, fz;
    sh_fields(pos, s, d, fx, fy, fz);
    unsigned long long p = ((unsigned long long)fx << 48)
                         | ((unsigned long long)fy << 32)
                         | ((unsigned long long)fz << 16) | 1ull;
    unsigned r = (unsigned)blockIdx.x & (unsigned)rmask;
    atomicAdd(acc + (size_t)r * (unsigned)n_nodes + (unsigned)d, p);
}

__global__ void finalize_flat(const unsigned long long* __restrict__ acc,
                              const float* __restrict__ feat,
                              const float* __restrict__ w0,
                              const float* __restrict__ w1,
                              float* __restrict__ out,
                              int n_nodes, int R) {
    int n = blockIdx.x * blockDim.x + threadIdx.x;
    if (n >= n_nodes) return;
    int Fx = 0, Fy = 0, Fz = 0, C = 0;
    for (int r = 0; r < R; ++r) {
        unsigned long long v = acc[(size_t)r * n_nodes + n];
        Fx += (int)(v >> 48);
        Fy += (int)((v >> 32) & 0xffffull);
        Fz += (int)((v >> 16) & 0xffffull);
        C  += (int)(v & 0xffffull);
    }
    float c = (float)C;
    float rd = 1.0f / fmaxf(c, 1.0f);
    float sx = (float)Fx * (1.0f / FSCALE) - c;
    float sy = (float)Fy * (1.0f / FSCALE) - c;
    float sz = (float)Fz * (1.0f / FSCALE) - c;
    float f = feat[n];
    float4 o;
    o.x = w0[0] * f * c * rd;
    o.y = w1[0] * f * sx * rd;
    o.z = w1[1] * f * sy * rd;
    o.w = w1[2] * f * sz * rd;
    ((float4*)out)[n] = o;
}

extern "C" void kernel_launch(void* const* d_in, const int* in_sizes, int n_in,
                              void* d_out, int out_size, void* d_ws, size_t ws_size,
                              hipStream_t stream) {
    const float* pos  = (const float*)d_in[0];
    const float* feat = (const float*)d_in[1];
    const float* w0   = (const float*)d_in[2];
    const float* w1   = (const float*)d_in[3];
    const int* esrc   = (const int*)d_in[4];
    const int* edst   = (const int*)d_in[5];
    int n_nodes = in_sizes[0] / 3;
    int n_edges = in_sizes[4];

    int n_chunk = (n_nodes + CHUNK - 1) >> CHUNK_SHIFT;      // 13 for 100k
    int padded  = n_chunk * CHUNK;
    // bucket capacity: expected chunk load + generous slack
    int cap = (int)((long)n_edges * CHUNK / n_nodes + 8192);

    size_t off_gcnt = 0;
    size_t off_recs = 256;
    size_t recs_bytes = (size_t)n_chunk * (unsigned)cap * sizeof(unsigned long long);
    size_t off_accR = off_recs + ((recs_bytes + 255) & ~(size_t)255);
    size_t accR_bytes = (size_t)SUBS * (unsigned)padded * sizeof(unsigned long long);
    size_t need = off_accR + accR_bytes;

    int nb = 256;
    int ng = (n_nodes + nb - 1) / nb;

    if (n_chunk <= NCHUNK_MAX && ws_size >= need) {
        unsigned* gcnt = (unsigned*)((char*)d_ws + off_gcnt);
        unsigned long long* recs = (unsigned long long*)((char*)d_ws + off_recs);
        unsigned long long* accR = (unsigned long long*)((char*)d_ws + off_accR);

        hipMemsetAsync(gcnt, 0, (size_t)n_chunk * sizeof(unsigned), stream);

        int ga = (int)((n_edges + (long)BLKA * TPA - 1) / ((long)BLKA * TPA));
        phaseA<<<ga, BLKA, 0, stream>>>(pos, edst, esrc, gcnt, recs,
                                        n_edges, cap, n_chunk);
        phaseB<<<n_chunk * SUBS, BLKB, 0, stream>>>(gcnt, recs, accR,
                                                    cap, n_chunk, padded);
        finalize_binned<<<ng, nb, 0, stream>>>(accR, feat, w0, w1,
                                               (float*)d_out, n_nodes, padded);
    } else {
        // fallback: R3 known-good agent-atomic path
        int R = 4;
        while (R > 1 && (size_t)R * n_nodes * sizeof(unsigned long long) > ws_size) R >>= 1;
        unsigned long long* acc = (unsigned long long*)d_ws;
        hipMemsetAsync(acc, 0, (size_t)R * n_nodes * sizeof(unsigned long long), stream);
        int eb = 256;
        int eg = (n_edges + eb - 1) / eb;
        edge_kernel_agent<<<eg, eb, 0, stream>>>(pos, edst, esrc, acc,
                                                 n_edges, n_nodes, R - 1);
        finalize_flat<<<ng, nb, 0, stream>>>(acc, feat, w0, w1,
                                             (float*)d_out, n_nodes, R);
    }
}